// Round 5
// baseline (601.342 us; speedup 1.0000x reference)
//
#include <hip/hip_runtime.h>
#include <cmath>

// MHSA cosine-attention block, MI355X/gfx950.  Round 15.
// FUSED single kernel with SOFTWARE grid barrier (R14's cooperative launch
// silently no-opped under graph capture -> all-zero output).
// grid: 1024 blocks x 256 thr = exactly 4 blocks/CU (LDS 34816 B,
// launch_bounds(256,4)) -- same resources as R13's k2, so full
// co-residency is guaranteed and the spin barrier cannot deadlock.
//   phase 1: QKV projection+normalize, 16-l tiles (blocks 0..511)
//   barrier(1024)
//   phase 2: flash attention, R13-proven body (all 1024 blocks)
//   barrier(2048)
//   phase 3: partial reduce + projection + residual (blocks 0..511)
// Coherence across XCDs: __threadfence release + agent-scope atomics +
// acquire fence after the barrier (Guideline 16).

typedef __bf16 bf16x8 __attribute__((ext_vector_type(8)));
typedef __bf16 bf16x4 __attribute__((ext_vector_type(4)));
typedef float f4_t __attribute__((ext_vector_type(4)));

#define LQ 4096       // sequence length H*W
#define NH 4          // n*heads
#define KS 8          // key splits

__device__ inline f4_t mfma16(bf16x8 a, bf16x8 b, f4_t c) {
    return __builtin_amdgcn_mfma_f32_16x16x32_bf16(a, b, c, 0, 0, 0);
}

__device__ inline bf16x8 cvt8(const float* p) {
    f4_t a = *(const f4_t*)p, b = *(const f4_t*)(p + 4);
    bf16x8 r;
    r[0] = (__bf16)a[0]; r[1] = (__bf16)a[1]; r[2] = (__bf16)a[2]; r[3] = (__bf16)a[3];
    r[4] = (__bf16)b[0]; r[5] = (__bf16)b[1]; r[6] = (__bf16)b[2]; r[7] = (__bf16)b[3];
    return r;
}

// direct global->LDS DMA, 16 B per lane; lds dest must be wave-uniform base
__device__ inline void gload_lds16(const __bf16* g, __bf16* l) {
    __builtin_amdgcn_global_load_lds(
        (const __attribute__((address_space(1))) void*)g,
        (__attribute__((address_space(3))) void*)l, 16, 0, 0);
}

// software grid barrier: all 1024 blocks are co-resident (exact-capacity
// launch), so spinning is deadlock-free.  Release fence before arrive,
// acquire fence after depart (cross-XCD L2 visibility).
__device__ inline void grid_barrier(unsigned* cnt, unsigned target) {
    __syncthreads();
    __threadfence();                       // release this block's writes
    if (threadIdx.x == 0) {
        __hip_atomic_fetch_add(cnt, 1u, __ATOMIC_ACQ_REL,
                               __HIP_MEMORY_SCOPE_AGENT);
        unsigned v;
        do {
            v = __hip_atomic_load(cnt, __ATOMIC_ACQUIRE,
                                  __HIP_MEMORY_SCOPE_AGENT);
            if (v < target) __builtin_amdgcn_s_sleep(2);
        } while (v < target);
    }
    __syncthreads();
    __threadfence();                       // acquire: invalidate stale lines
}

// ---------------------------------------------------------------------------
// Fused kernel.  grid: 1024 blocks x 256 thr.  LDS: 34816 B union.
// ---------------------------------------------------------------------------
__global__ __launch_bounds__(256, 4) void k_fused(
        const float* __restrict__ x,
        const float* __restrict__ Wq, const float* __restrict__ bq,
        const float* __restrict__ Wk, const float* __restrict__ bk,
        const float* __restrict__ Wv, const float* __restrict__ bv,
        const float* __restrict__ Wm, const float* __restrict__ bm,
        float* __restrict__ out,
        __bf16* __restrict__ Qb, __bf16* __restrict__ Kb,
        __bf16* __restrict__ Vtb,
        __bf16* __restrict__ numPb, float* __restrict__ denP,
        unsigned* __restrict__ bar) {
    const int tid  = threadIdx.x;
    const int lane = tid & 63;
    const int w    = tid >> 6;     // wave
    const int quad = lane >> 4;
    const int l15  = lane & 15;
    const int b    = blockIdx.x;

    __shared__ __align__(16) unsigned char smem[34816];

    // =====================================================================
    // Phase 1: QKV projection + normalize.  blocks 0..511, 16-l tiles.
    // =====================================================================
    if (b < 512) {
        const int n  = b >> 8;
        const int l0 = (b & 255) * 16;

        __bf16 (*xl)[72] = (__bf16 (*)[72])smem;   // [16][72]

        {
            const int c0 = tid >> 4, l = tid & 15;
#pragma unroll
            for (int i = 0; i < 4; ++i) {
                const int c = c0 + i * 16;
                xl[l][c] = (__bf16)x[((size_t)n * 64 + c) * LQ + l0 + l];
            }
        }

        const float* Wqk = (w < 2) ? Wq : Wk;
        const float* bqk = (w < 2) ? bq : bk;
        const int h = w & 1;

        bf16x8 af[4][2], av[2];
#pragma unroll
        for (int t = 0; t < 4; ++t)
#pragma unroll
            for (int kh = 0; kh < 2; ++kh)
                af[t][kh] = cvt8(Wqk + (size_t)(h * 64 + t * 16 + l15) * 64
                                      + kh * 32 + quad * 8);
#pragma unroll
        for (int kh = 0; kh < 2; ++kh)
            av[kh] = cvt8(Wv + (size_t)(w * 16 + l15) * 64 + kh * 32 + quad * 8);

        f4_t binit[4], bvinit;
#pragma unroll
        for (int t = 0; t < 4; ++t)
#pragma unroll
            for (int r = 0; r < 4; ++r)
                binit[t][r] = bqk[h * 64 + t * 16 + quad * 4 + r];
#pragma unroll
        for (int r = 0; r < 4; ++r)
            bvinit[r] = bv[w * 16 + quad * 4 + r];

        __syncthreads();

        f4_t acc[4], vacc;
        {
            bf16x8 bf0 = *(const bf16x8*)&xl[l15][quad * 8];
            bf16x8 bf1 = *(const bf16x8*)&xl[l15][32 + quad * 8];
#pragma unroll
            for (int t = 0; t < 4; ++t) {
                f4_t a = mfma16(af[t][0], bf0, binit[t]);
                acc[t] = mfma16(af[t][1], bf1, a);
            }
            f4_t va = mfma16(av[0], bf0, bvinit);
            vacc = mfma16(av[1], bf1, va);
        }

        const int nh = n * 2 + h;
        __bf16* dst  = (w < 2) ? Qb : Kb;
        const float post = (w < 2) ? 1.44269504f : 1.0f;

        float ss = 0.f;
#pragma unroll
        for (int t = 0; t < 4; ++t)
#pragma unroll
            for (int r = 0; r < 4; ++r)
                ss = fmaf(acc[t][r], acc[t][r], ss);
        ss += __shfl_xor(ss, 16, 64);
        ss += __shfl_xor(ss, 32, 64);
        const float rn = post / fmaxf(sqrtf(ss), 1e-6f);

        const int l = l0 + l15;
#pragma unroll
        for (int t = 0; t < 4; ++t) {
            bf16x4 pk;
#pragma unroll
            for (int r = 0; r < 4; ++r) pk[r] = (__bf16)(acc[t][r] * rn);
            const int kc = t * 2 + (quad >> 1);
            *(bf16x4*)(dst + ((size_t)(nh * 8 + kc) * LQ + l) * 8 + (quad & 1) * 4) = pk;
        }
#pragma unroll
        for (int r = 0; r < 4; ++r) {
            const int vrow = w * 16 + quad * 4 + r;
            Vtb[(size_t)(n * 64 + vrow) * LQ + l] = (__bf16)vacc[r];
        }
    }

    grid_barrier(bar, 1024);

    // =====================================================================
    // Phase 2: flash attention (R13 body).  all 1024 blocks.
    // b -> (qb = b&31, nh = (b>>5)&3, ks = b>>7)
    // =====================================================================
    {
        const int wave = w;
        const int nh   = (b >> 5) & 3;
        const int ks   = b >> 7;
        const int qbase = (b & 31) * 128 + wave * 32;
        const int kbase = ks * 512;

        __bf16 (*Kl)[4096] = (__bf16 (*)[4096])smem;                 // [2][4096]
        __bf16 (*P)[2][16][72] = (__bf16 (*)[2][16][72])(smem + 16384); // [4][..]

        const f4_t fzero = {0.f, 0.f, 0.f, 0.f};

        const __bf16* s_src0, * s_src1;
        {
            const int s0 = tid, s1 = tid + 256;
            const int kc0 = ((s0 >> 6) & 1) * 4 + ((s0 >> 4) & 3);
            const int ll0 = (s0 >> 7) * 16 + (s0 & 15);
            const int kc1 = ((s1 >> 6) & 1) * 4 + ((s1 >> 4) & 3);
            const int ll1 = (s1 >> 7) * 16 + (s1 & 15);
            s_src0 = Kb + ((size_t)(nh * 8 + kc0) * LQ + kbase + ll0) * 8;
            s_src1 = Kb + ((size_t)(nh * 8 + kc1) * LQ + kbase + ll1) * 8;
        }

        bf16x8 qf[2][2];
#pragma unroll
        for (int qt = 0; qt < 2; ++qt)
#pragma unroll
            for (int kh = 0; kh < 2; ++kh)
                qf[qt][kh] = *(const bf16x8*)(Qb +
                    ((size_t)(nh * 8 + kh * 4 + quad) * LQ + qbase + qt * 16 + l15) * 8);

        f4_t racc[2][2];
#pragma unroll
        for (int a = 0; a < 2; ++a)
#pragma unroll
            for (int c = 0; c < 2; ++c) racc[a][c] = fzero;
        float den[2] = {0.f, 0.f};

        const __bf16* v_src = Vtb + (size_t)(nh * 32 + l15) * LQ + kbase + quad * 8;

        gload_lds16(s_src0, &Kl[0][wave * 512]);
        gload_lds16(s_src1, &Kl[0][2048 + wave * 512]);
        __syncthreads();

#pragma unroll 2
        for (int ch = 0; ch < 8; ++ch) {
            const int cur = ch & 1;

            if (ch < 7) {
                gload_lds16(s_src0 + (size_t)(ch + 1) * 512,
                            &Kl[cur ^ 1][wave * 512]);
                gload_lds16(s_src1 + (size_t)(ch + 1) * 512,
                            &Kl[cur ^ 1][2048 + wave * 512]);
            }

            bf16x8 vf[2][2];
#pragma unroll
            for (int vt = 0; vt < 2; ++vt)
#pragma unroll
                for (int kp = 0; kp < 2; ++kp)
                    vf[vt][kp] = *(const bf16x8*)(v_src + (size_t)vt * 16 * LQ
                                                  + ch * 64 + kp * 32);

#pragma unroll
            for (int ktp = 0; ktp < 2; ++ktp) {
                bf16x8 kf[2][2];
#pragma unroll
                for (int i = 0; i < 2; ++i)
#pragma unroll
                    for (int kh = 0; kh < 2; ++kh)
                        kf[i][kh] = *(const bf16x8*)
                            &Kl[cur][(size_t)((ktp * 2 + i) * 128 + kh * 64
                                              + quad * 16 + l15) * 8];

                f4_t s[2][2];
#pragma unroll
                for (int qt = 0; qt < 2; ++qt)
#pragma unroll
                    for (int i = 0; i < 2; ++i) {
                        f4_t t = mfma16(kf[i][0], qf[qt][0], fzero);
                        s[qt][i] = mfma16(kf[i][1], qf[qt][1], t);
                    }

#pragma unroll
                for (int qt = 0; qt < 2; ++qt)
#pragma unroll
                    for (int i = 0; i < 2; ++i) {
                        bf16x4 pv;
                        float d = 0.f;
#pragma unroll
                        for (int r = 0; r < 4; ++r) {
                            float p = __builtin_exp2f(s[qt][i][r]);
                            d += p;
                            pv[r] = (__bf16)p;
                        }
                        den[qt] += d;
                        *(bf16x4*)&P[wave][qt][l15][(ktp * 2 + i) * 16 + quad * 4] = pv;
                    }
            }

#pragma unroll
            for (int qt = 0; qt < 2; ++qt)
#pragma unroll
                for (int kp = 0; kp < 2; ++kp) {
                    bf16x8 pf = *(const bf16x8*)&P[wave][qt][l15][kp * 32 + quad * 8];
                    racc[0][qt] = mfma16(vf[0][kp], pf, racc[0][qt]);
                    racc[1][qt] = mfma16(vf[1][kp], pf, racc[1][qt]);
                }

            __syncthreads();
        }

#pragma unroll
        for (int qt = 0; qt < 2; ++qt) {
            den[qt] += __shfl_xor(den[qt], 16, 64);
            den[qt] += __shfl_xor(den[qt], 32, 64);
        }

        const size_t pb = (size_t)(nh * KS + ks) * LQ;
#pragma unroll
        for (int vt = 0; vt < 2; ++vt)
#pragma unroll
            for (int qt = 0; qt < 2; ++qt) {
                bf16x4 pk;
#pragma unroll
                for (int r = 0; r < 4; ++r) pk[r] = (__bf16)racc[vt][qt][r];
                *(bf16x4*)(numPb + (pb + qbase + qt * 16 + l15) * 32
                                 + vt * 16 + quad * 4) = pk;
            }

        if (lane < 16)
#pragma unroll
            for (int qt = 0; qt < 2; ++qt)
                denP[pb + qbase + qt * 16 + lane] = den[qt];
    }

    grid_barrier(bar, 2048);

    // =====================================================================
    // Phase 3: partial reduce -> projection + residual.  blocks 0..511.
    // =====================================================================
    if (b < 512) {
        const int n  = b >> 8;
        const int l0 = (b & 255) * 16;

        float (*Rps)[64][17] = (float (*)[64][17])smem;          // [2][64][17]
        float (*dinv)[16]    = (float (*)[16])(smem + 8704);     // [2][16]

        if (tid < 32) {
            const int hh = tid >> 4, li = tid & 15;
            float s = 0.f;
#pragma unroll
            for (int k = 0; k < KS; ++k)
                s += denP[(size_t)((n * 2 + hh) * KS + k) * LQ + l0 + li];
            dinv[hh][li] = 1.0f / s;
        }

        {
            const int vg = tid & 3, l = (tid >> 2) & 15;
            const int hh = (tid >> 6) & 1, sh = tid >> 7;
            const size_t base = (size_t)(n * 2 + hh) * KS * LQ;
            float a[8] = {0.f, 0.f, 0.f, 0.f, 0.f, 0.f, 0.f, 0.f};
#pragma unroll
            for (int k = 0; k < 4; ++k) {
                const int kk = sh * 4 + k;
                bf16x8 v8 = *(const bf16x8*)(numPb +
                    (base + (size_t)kk * LQ + l0 + l) * 32 + vg * 8);
#pragma unroll
                for (int j = 0; j < 8; ++j) a[j] += (float)v8[j];
            }
#pragma unroll
            for (int j = 0; j < 8; ++j)
                Rps[sh][hh * 32 + vg * 8 + j][l] = a[j];
        }
        __syncthreads();

        const int l = tid & 15, og = tid >> 4;
        const float d0 = dinv[0][l], d1 = dinv[1][l];
        float rj[64];
#pragma unroll
        for (int j = 0; j < 64; ++j)
            rj[j] = (Rps[0][j][l] + Rps[1][j][l]) * (j < 32 ? d0 : d1);

#pragma unroll
        for (int oi = 0; oi < 4; ++oi) {
            const int o = og * 4 + oi;
            const float* wr = Wm + (size_t)o * 64;
            float a = bm[o];
#pragma unroll
            for (int j4 = 0; j4 < 16; ++j4) {
                f4_t t = *(const f4_t*)(wr + j4 * 4);
                a = fmaf(t[0], rj[j4 * 4 + 0], a);
                a = fmaf(t[1], rj[j4 * 4 + 1], a);
                a = fmaf(t[2], rj[j4 * 4 + 2], a);
                a = fmaf(t[3], rj[j4 * 4 + 3], a);
            }
            const size_t idx = (size_t)(n * 64 + o) * LQ + l0 + l;
            out[idx] = a + x[idx];
        }
    }
}

// ---------------------------------------------------------------------------
extern "C" void kernel_launch(void* const* d_in, const int* in_sizes, int n_in,
                              void* d_out, int out_size, void* d_ws, size_t ws_size,
                              hipStream_t stream) {
    const float* x  = (const float*)d_in[0];
    const float* Wq = (const float*)d_in[1];
    const float* bq = (const float*)d_in[2];
    const float* Wk = (const float*)d_in[3];
    const float* bk = (const float*)d_in[4];
    const float* Wv = (const float*)d_in[5];
    const float* bv = (const float*)d_in[6];
    const float* Wm = (const float*)d_in[7];
    const float* bm = (const float*)d_in[8];
    float* out = (float*)d_out;

    // workspace carve: Qb 2MB | Kb 2MB | Vtb 1MB | numPb 8.4MB | denP 0.5MB
    // | barrier counter (64B, memset to 0 each iteration)
    __bf16* Qb    = (__bf16*)d_ws;
    __bf16* Kb    = Qb + (size_t)NH * LQ * 64;
    __bf16* Vtb   = Kb + (size_t)NH * LQ * 64;
    __bf16* numPb = Vtb + (size_t)NH * 32 * LQ;
    float*  denP  = (float*)(numPb + (size_t)NH * KS * LQ * 32);
    unsigned* bar = (unsigned*)(denP + (size_t)NH * KS * LQ);

    hipMemsetAsync(bar, 0, 64, stream);
    k_fused<<<dim3(1024), dim3(256), 0, stream>>>(
        x, Wq, bq, Wk, bk, Wv, bv, Wm, bm, out,
        Qb, Kb, Vtb, numPb, denP, bar);
}

// Round 6
// 115.022 us; speedup vs baseline: 5.2280x; 5.2280x over previous
//
#include <hip/hip_runtime.h>
#include <cmath>

// MHSA cosine-attention block, MI355X/gfx950.  Round 16.
// K1: QKV projection as MFMA GEMM (R8/R9). Q pre-scaled by log2e.
// K2: BARRIER-FREE flash attention.  R15's counters showed k2 is
//     stall-bound (~2x pipe-sum).  The only cross-wave coupling was the
//     K LDS double-buffer; K fragments are b128-contiguous directly in
//     Kb's k8-tiled layout, and the K slice (4 MB total) is L2-resident
//     (128x reuse).  So: K streams straight from global (8 b128/chunk,
//     32 VGPR transient), P stays wave-private LDS, and the chunk loop
//     has NO __syncthreads at all.  LDS 34.8 -> 18.4 KB.
//     (Distinct from R10's failed register-K, which held all 512 keys.)
// K3: vectorized bf16 partial reduce (b128 numPb loads), unchanged.
// (R14/R15 fusion refuted: coop-launch no-ops under graph capture; SW
//  grid barrier costs ~250 us/barrier from same-line atomic serialization.)

typedef __bf16 bf16x8 __attribute__((ext_vector_type(8)));
typedef __bf16 bf16x4 __attribute__((ext_vector_type(4)));
typedef float f4_t __attribute__((ext_vector_type(4)));

#define LQ 4096       // sequence length H*W
#define NH 4          // n*heads
#define KS 8          // key splits

__device__ inline f4_t mfma16(bf16x8 a, bf16x8 b, f4_t c) {
    return __builtin_amdgcn_mfma_f32_16x16x32_bf16(a, b, c, 0, 0, 0);
}

__device__ inline bf16x8 cvt8(const float* p) {
    f4_t a = *(const f4_t*)p, b = *(const f4_t*)(p + 4);
    bf16x8 r;
    r[0] = (__bf16)a[0]; r[1] = (__bf16)a[1]; r[2] = (__bf16)a[2]; r[3] = (__bf16)a[3];
    r[4] = (__bf16)b[0]; r[5] = (__bf16)b[1]; r[6] = (__bf16)b[2]; r[7] = (__bf16)b[3];
    return r;
}

// ---------------------------------------------------------------------------
// Kernel 1: QKV projection + normalize via MFMA.
// grid: dim3(128, 2) = l-tile(32) x n.  block: 256 thr = 4 waves.
// ---------------------------------------------------------------------------
__global__ __launch_bounds__(256) void k1_qkv(
        const float* __restrict__ x,
        const float* __restrict__ Wq, const float* __restrict__ bq,
        const float* __restrict__ Wk, const float* __restrict__ bk,
        const float* __restrict__ Wv, const float* __restrict__ bv,
        __bf16* __restrict__ Qb, __bf16* __restrict__ Kb,
        __bf16* __restrict__ Vtb) {
    const int tid  = threadIdx.x;
    const int lane = tid & 63;
    const int w    = tid >> 6;
    const int quad = lane >> 4;
    const int l15  = lane & 15;
    const int lt   = blockIdx.x;
    const int n    = blockIdx.y;
    const int l0   = lt * 32;

    __shared__ __bf16 xl[32][72];   // [l][c] bf16, pitch 72

    {
        const int c0 = tid >> 5, l = tid & 31;
#pragma unroll
        for (int i = 0; i < 8; ++i) {
            const int c = c0 + i * 8;
            xl[l][c] = (__bf16)x[((size_t)n * 64 + c) * LQ + l0 + l];
        }
    }

    const float* Wqk = (w < 2) ? Wq : Wk;
    const float* bqk = (w < 2) ? bq : bk;
    const int h = w & 1;

    bf16x8 af[4][2], av[2];
#pragma unroll
    for (int t = 0; t < 4; ++t)
#pragma unroll
        for (int kh = 0; kh < 2; ++kh)
            af[t][kh] = cvt8(Wqk + (size_t)(h * 64 + t * 16 + l15) * 64
                                  + kh * 32 + quad * 8);
#pragma unroll
    for (int kh = 0; kh < 2; ++kh)
        av[kh] = cvt8(Wv + (size_t)(w * 16 + l15) * 64 + kh * 32 + quad * 8);

    f4_t binit[4], bvinit;
#pragma unroll
    for (int t = 0; t < 4; ++t)
#pragma unroll
        for (int r = 0; r < 4; ++r)
            binit[t][r] = bqk[h * 64 + t * 16 + quad * 4 + r];
#pragma unroll
    for (int r = 0; r < 4; ++r)
        bvinit[r] = bv[w * 16 + quad * 4 + r];

    __syncthreads();

    f4_t acc[4][2], vacc[2];
#pragma unroll
    for (int lsub = 0; lsub < 2; ++lsub) {
        bf16x8 bf0 = *(const bf16x8*)&xl[lsub * 16 + l15][quad * 8];
        bf16x8 bf1 = *(const bf16x8*)&xl[lsub * 16 + l15][32 + quad * 8];
#pragma unroll
        for (int t = 0; t < 4; ++t) {
            f4_t a = mfma16(af[t][0], bf0, binit[t]);
            acc[t][lsub] = mfma16(af[t][1], bf1, a);
        }
        f4_t va = mfma16(av[0], bf0, bvinit);
        vacc[lsub] = mfma16(av[1], bf1, va);
    }

    const int nh = n * 2 + h;
    __bf16* dst  = (w < 2) ? Qb : Kb;
    const float post = (w < 2) ? 1.44269504f : 1.0f;
#pragma unroll
    for (int lsub = 0; lsub < 2; ++lsub) {
        float ss = 0.f;
#pragma unroll
        for (int t = 0; t < 4; ++t)
#pragma unroll
            for (int r = 0; r < 4; ++r)
                ss = fmaf(acc[t][lsub][r], acc[t][lsub][r], ss);
        ss += __shfl_xor(ss, 16, 64);
        ss += __shfl_xor(ss, 32, 64);
        const float rn = post / fmaxf(sqrtf(ss), 1e-6f);

        const int l = l0 + lsub * 16 + l15;
#pragma unroll
        for (int t = 0; t < 4; ++t) {
            bf16x4 pk;
#pragma unroll
            for (int r = 0; r < 4; ++r) pk[r] = (__bf16)(acc[t][lsub][r] * rn);
            const int kc = t * 2 + (quad >> 1);
            *(bf16x4*)(dst + ((size_t)(nh * 8 + kc) * LQ + l) * 8 + (quad & 1) * 4) = pk;
        }
#pragma unroll
        for (int r = 0; r < 4; ++r) {
            const int vrow = w * 16 + quad * 4 + r;
            Vtb[(size_t)(n * 64 + vrow) * LQ + l] = (__bf16)vacc[lsub][r];
        }
    }
}

// ---------------------------------------------------------------------------
// Kernel 2: barrier-free flash attention.
// grid: (32 q-blocks of 128, nh=4, ks=8) = 1024 blocks x 4 waves.
// 8 chunks x 64 keys; K fragments loaded b128 DIRECTLY from global
// (Kb's k8-tiled layout: lane(quad,l15) reads 16B at
// ((nh*8 + kh*4+quad)*LQ + key)*8, key = kbase+ch*64+kt*16+l15).
// P stays wave-private LDS (in-order same-wave DS round trip).
// No __syncthreads anywhere in the loop; waves fully independent.
// ---------------------------------------------------------------------------
__global__ __launch_bounds__(256, 4) void k2_attn(
        const __bf16* __restrict__ Qb, const __bf16* __restrict__ Kb,
        const __bf16* __restrict__ Vtb,
        __bf16* __restrict__ numPb, float* __restrict__ denP) {
    const int tid  = threadIdx.x;
    const int lane = tid & 63;
    const int wave = tid >> 6;
    const int quad = lane >> 4;
    const int l15  = lane & 15;
    const int nh   = blockIdx.y;
    const int ks   = blockIdx.z;
    const int qbase = blockIdx.x * 128 + wave * 32;
    const int kbase = ks * 512;

    __shared__ __bf16 P[4][2][16][72];   // [wave][qt][q-row][64 keys + pad]

    const f4_t fzero = {0.f, 0.f, 0.f, 0.f};

    // Q fragments (k8-tiled layout), reused for all 512 keys
    bf16x8 qf[2][2];
#pragma unroll
    for (int qt = 0; qt < 2; ++qt)
#pragma unroll
        for (int kh = 0; kh < 2; ++kh)
            qf[qt][kh] = *(const bf16x8*)(Qb +
                ((size_t)(nh * 8 + kh * 4 + quad) * LQ + qbase + qt * 16 + l15) * 8);

    f4_t racc[2][2];                     // [vt][qt]
#pragma unroll
    for (int a = 0; a < 2; ++a)
#pragma unroll
        for (int b = 0; b < 2; ++b) racc[a][b] = fzero;
    float den[2] = {0.f, 0.f};

    // K base: lane reads K[key = ch*64 + kt*16 + l15][dk = (kh*4+quad)*8..+8]
    const __bf16* k_base = Kb + ((size_t)(nh * 8 + quad) * LQ + kbase + l15) * 8;
    // V base: lane reads V[v = vt*16+l15][key = kp*32 + quad*8 ..+8]
    const __bf16* v_src = Vtb + (size_t)(nh * 32 + l15) * LQ + kbase + quad * 8;

#pragma unroll 2
    for (int ch = 0; ch < 8; ++ch) {
        // all global loads for this chunk issued up front (no barriers --
        // the compiler batches them and can overlap across iterations)
        bf16x8 kf[4][2];   // [kt][kh]
#pragma unroll
        for (int kt = 0; kt < 4; ++kt)
#pragma unroll
            for (int kh = 0; kh < 2; ++kh)
                kf[kt][kh] = *(const bf16x8*)(k_base +
                    ((size_t)kh * 4 * LQ + ch * 64 + kt * 16) * 8);

        bf16x8 vf[2][2];   // [vt][kp]
#pragma unroll
        for (int vt = 0; vt < 2; ++vt)
#pragma unroll
            for (int kp = 0; kp < 2; ++kp)
                vf[vt][kp] = *(const bf16x8*)(v_src + (size_t)vt * 16 * LQ
                                              + ch * 64 + kp * 32);

        // S^T + exp in 2 key-tile pairs
#pragma unroll
        for (int ktp = 0; ktp < 2; ++ktp) {
            f4_t s[2][2];
#pragma unroll
            for (int qt = 0; qt < 2; ++qt)
#pragma unroll
                for (int i = 0; i < 2; ++i) {
                    f4_t t = mfma16(kf[ktp * 2 + i][0], qf[qt][0], fzero);
                    s[qt][i] = mfma16(kf[ktp * 2 + i][1], qf[qt][1], t);
                }

#pragma unroll
            for (int qt = 0; qt < 2; ++qt)
#pragma unroll
                for (int i = 0; i < 2; ++i) {
                    bf16x4 pv;
                    float d = 0.f;
#pragma unroll
                    for (int r = 0; r < 4; ++r) {
                        float p = __builtin_exp2f(s[qt][i][r]);
                        d += p;
                        pv[r] = (__bf16)p;
                    }
                    den[qt] += d;
                    *(bf16x4*)&P[wave][qt][l15][(ktp * 2 + i) * 16 + quad * 4] = pv;
                }
        }

        // PV: A = V rows, B = P rows (same-wave LDS, in-order DS)
#pragma unroll
        for (int qt = 0; qt < 2; ++qt)
#pragma unroll
            for (int kp = 0; kp < 2; ++kp) {
                bf16x8 pf = *(const bf16x8*)&P[wave][qt][l15][kp * 32 + quad * 8];
                racc[0][qt] = mfma16(vf[0][kp], pf, racc[0][qt]);
                racc[1][qt] = mfma16(vf[1][kp], pf, racc[1][qt]);
            }
    }

    // den: reduce quad partials (same q = l15 across quads)
#pragma unroll
    for (int qt = 0; qt < 2; ++qt) {
        den[qt] += __shfl_xor(den[qt], 16, 64);
        den[qt] += __shfl_xor(den[qt], 32, 64);
    }

    const size_t pb = (size_t)(nh * KS + ks) * LQ;
    // numPb layout [nh][ks][q][v32] bf16 -- v-contiguous for k3
#pragma unroll
    for (int vt = 0; vt < 2; ++vt)
#pragma unroll
        for (int qt = 0; qt < 2; ++qt) {
            bf16x4 pk;
#pragma unroll
            for (int r = 0; r < 4; ++r) pk[r] = (__bf16)racc[vt][qt][r];
            *(bf16x4*)(numPb + (pb + qbase + qt * 16 + l15) * 32
                             + vt * 16 + quad * 4) = pk;
        }

    if (lane < 16)
#pragma unroll
        for (int qt = 0; qt < 2; ++qt)
            denP[pb + qbase + qt * 16 + lane] = den[qt];
}

// ---------------------------------------------------------------------------
// Kernel 3: vectorized bf16 partial reduce -> R, fp32 projection + residual.
// grid: dim3(256, 2) = l-tile(16) x n = 512 blocks.  block: 256 thr.
// Reduce map: tid = sh(1)|hh(1)|l(4)|vg(2) -> each thread 4x b128 loads,
// per-wave address span contiguous 1 KB per instruction.
// ---------------------------------------------------------------------------
__global__ __launch_bounds__(256) void k3_out(
        const __bf16* __restrict__ numPb, const float* __restrict__ denP,
        const float* __restrict__ Wm, const float* __restrict__ bm,
        const float* __restrict__ x, float* __restrict__ out) {
    const int tid = threadIdx.x;
    const int lt  = blockIdx.x;
    const int n   = blockIdx.y;
    const int l0  = lt * 16;

    __shared__ float Rps[2][64][17];   // [ks-half][j = h*32+v][l]
    __shared__ float dinv[2][16];

    if (tid < 32) {
        const int hh = tid >> 4, li = tid & 15;
        float s = 0.f;
#pragma unroll
        for (int k = 0; k < KS; ++k)
            s += denP[(size_t)((n * 2 + hh) * KS + k) * LQ + l0 + li];
        dinv[hh][li] = 1.0f / s;
    }

    // vectorized reduce over ks (two halves in parallel)
    {
        const int vg = tid & 3, l = (tid >> 2) & 15;
        const int hh = (tid >> 6) & 1, sh = tid >> 7;
        const size_t base = (size_t)(n * 2 + hh) * KS * LQ;
        float a[8] = {0.f, 0.f, 0.f, 0.f, 0.f, 0.f, 0.f, 0.f};
#pragma unroll
        for (int k = 0; k < 4; ++k) {
            const int kk = sh * 4 + k;
            bf16x8 v8 = *(const bf16x8*)(numPb +
                (base + (size_t)kk * LQ + l0 + l) * 32 + vg * 8);
#pragma unroll
            for (int j = 0; j < 8; ++j) a[j] += (float)v8[j];
        }
#pragma unroll
        for (int j = 0; j < 8; ++j)
            Rps[sh][hh * 32 + vg * 8 + j][l] = a[j];
    }
    __syncthreads();

    // projection: thread (l = tid&15, og = tid>>4) -> outputs og*4..+3
    const int l = tid & 15, og = tid >> 4;
    const float d0 = dinv[0][l], d1 = dinv[1][l];
    float rj[64];
#pragma unroll
    for (int j = 0; j < 64; ++j)
        rj[j] = (Rps[0][j][l] + Rps[1][j][l]) * (j < 32 ? d0 : d1);

#pragma unroll
    for (int oi = 0; oi < 4; ++oi) {
        const int o = og * 4 + oi;
        const float* wr = Wm + (size_t)o * 64;
        float a = bm[o];
#pragma unroll
        for (int j4 = 0; j4 < 16; ++j4) {
            f4_t t = *(const f4_t*)(wr + j4 * 4);
            a = fmaf(t[0], rj[j4 * 4 + 0], a);
            a = fmaf(t[1], rj[j4 * 4 + 1], a);
            a = fmaf(t[2], rj[j4 * 4 + 2], a);
            a = fmaf(t[3], rj[j4 * 4 + 3], a);
        }
        const size_t idx = (size_t)(n * 64 + o) * LQ + l0 + l;
        out[idx] = a + x[idx];
    }
}

// ---------------------------------------------------------------------------
extern "C" void kernel_launch(void* const* d_in, const int* in_sizes, int n_in,
                              void* d_out, int out_size, void* d_ws, size_t ws_size,
                              hipStream_t stream) {
    const float* x  = (const float*)d_in[0];
    const float* Wq = (const float*)d_in[1];
    const float* bq = (const float*)d_in[2];
    const float* Wk = (const float*)d_in[3];
    const float* bk = (const float*)d_in[4];
    const float* Wv = (const float*)d_in[5];
    const float* bv = (const float*)d_in[6];
    const float* Wm = (const float*)d_in[7];
    const float* bm = (const float*)d_in[8];
    float* out = (float*)d_out;

    // workspace carve: Qb 2MB | Kb 2MB | Vtb 1MB | numPb 8.4MB | denP 0.5MB
    __bf16* Qb    = (__bf16*)d_ws;
    __bf16* Kb    = Qb + (size_t)NH * LQ * 64;
    __bf16* Vtb   = Kb + (size_t)NH * LQ * 64;
    __bf16* numPb = Vtb + (size_t)NH * 32 * LQ;
    float*  denP  = (float*)(numPb + (size_t)NH * KS * LQ * 32);

    k1_qkv<<<dim3(128, 2), dim3(256), 0, stream>>>(x, Wq, bq, Wk, bk, Wv, bv,
                                                   Qb, Kb, Vtb);
    k2_attn<<<dim3(32, NH, KS), dim3(256), 0, stream>>>(Qb, Kb, Vtb, numPb, denP);
    k3_out<<<dim3(256, 2), dim3(256), 0, stream>>>(numPb, denP, Wm, bm, x, out);
}